// Round 1
// 120.645 us; speedup vs baseline: 1.0293x; 1.0293x over previous
//
#include <hip/hip_runtime.h>
#include <hip/hip_bf16.h>

// GCN SpMM: out[i,d] = sum_{e: rows[e]==i} vals[e] * embeds[cols[e], d]
// rows sorted ascending. E=1.6M, N=100k, D=64.
//
// Round 8:
//  1) prep_kernel (merged): blocks [0,cvt_blocks) convert embeds f32->bf16
//     (12.8 MB table in d_ws); remaining blocks build CSR row_ptr[N+1].
//  2) spmm_node_kernel: 8-lane subgroups (8 nodes/wave), as round 7, PLUS
//     wave-cooperative LDS staging of cols/vals: a wave's 8 nodes own a
//     CONTIGUOUS edge span [row_ptr[8w], row_ptr[8w+8)), so the wave stages
//     up to 256 edges of cols+vals with coalesced loads into wave-private
//     LDS (no __syncthreads; DS ops are in-order per wave), and the inner
//     loop reads them via broadcast ds_read instead of 8 redundant
//     per-subgroup global loads per iteration. VMEM instruction count in
//     the hot loop drops ~2.4x (12/iter -> 4 gathers + ~1 amortized);
//     gather bytes unchanged (2 x 64B sectors per 128 B bf16 row).

constexpr int D = 64;

__device__ __forceinline__ unsigned bf16rnd(unsigned u) {
    // round-to-nearest-even f32 -> bf16 (low 16 bits)
    return (u + 0x7FFFu + ((u >> 16) & 1u)) >> 16;
}

__global__ __launch_bounds__(256) void prep_kernel(
    const uint4* __restrict__ src,   // f32 embeds as uint4 (2 per 8-float group)
    uint4* __restrict__ dst,         // bf16 table as uint4 (8 bf16)
    int n8,
    const int* __restrict__ rows, int* __restrict__ row_ptr,
    int n_edges, int n_nodes, int cvt_blocks)
{
    if ((int)blockIdx.x < cvt_blocks) {
        int i = blockIdx.x * 256 + threadIdx.x;
        if (i >= n8) return;
        uint4 a = src[2 * i];
        uint4 b = src[2 * i + 1];
        uint4 o;
        o.x = bf16rnd(a.x) | (bf16rnd(a.y) << 16);
        o.y = bf16rnd(a.z) | (bf16rnd(a.w) << 16);
        o.z = bf16rnd(b.x) | (bf16rnd(b.y) << 16);
        o.w = bf16rnd(b.z) | (bf16rnd(b.w) << 16);
        dst[i] = o;
    } else {
        int e = (blockIdx.x - cvt_blocks) * 256 + threadIdx.x;
        if (e >= n_edges) return;
        int r_cur  = rows[e];
        int r_prev = (e == 0) ? -1 : rows[e - 1];
        for (int r = r_prev + 1; r <= r_cur; ++r) row_ptr[r] = e;
        if (e == n_edges - 1)
            for (int r = r_cur + 1; r <= n_nodes; ++r) row_ptr[r] = n_edges;
    }
}

__device__ __forceinline__ float bflo(unsigned w) {
    union { unsigned u; float f; } x; x.u = w << 16; return x.f;
}
__device__ __forceinline__ float bfhi(unsigned w) {
    union { unsigned u; float f; } x; x.u = w & 0xFFFF0000u; return x.f;
}

__global__ __launch_bounds__(256) void spmm_node_kernel(
    const int* __restrict__ row_ptr,
    const int* __restrict__ cols,
    const float* __restrict__ vals,
    const uint4* __restrict__ ebf4,       // bf16 [N,64]: row = 8 uint4
    float4* __restrict__ out4,            // [N,16] float4 view
    int n_nodes)
{
    constexpr int CHUNK = 256;            // edges staged per wave per pass
    __shared__ int   s_cols[4][CHUNK];    // 4 waves/block, wave-private
    __shared__ float s_vals[4][CHUNK];

    const int lane = threadIdx.x & 63;
    const int t    = lane & 7;            // 16B chunk within row
    const int s    = lane >> 3;           // subgroup (node) within wave
    const int w    = threadIdx.x >> 6;    // wave within block
    const int wave = blockIdx.x * (blockDim.x >> 6) + w;
    const int node = wave * 8 + s;
    if (node >= n_nodes) return;

    const int nb    = wave * 8;
    const int nbhi  = (nb + 8 <= n_nodes) ? nb + 8 : n_nodes;
    const int wbase = row_ptr[nb];        // wave's contiguous edge span
    const int wend  = row_ptr[nbhi];
    const int lo    = row_ptr[node];
    const int hi    = row_ptr[node + 1];

    float4 acc0 = make_float4(0.f, 0.f, 0.f, 0.f);
    float4 acc1 = make_float4(0.f, 0.f, 0.f, 0.f);

    for (int cbase = wbase; cbase < wend; cbase += CHUNK) {
        // ---- cooperative, coalesced staging of this wave's edge chunk ----
        #pragma unroll
        for (int j = 0; j < CHUNK; j += 64) {
            if (cbase + j >= wend) break;         // wave-uniform early out
            int idx = cbase + j + lane;
            if (idx < wend) {
                s_cols[w][j + lane] = cols[idx];
                s_vals[w][j + lane] = vals[idx];
            }
        }
        __builtin_amdgcn_wave_barrier();  // pin ds_writes before ds_reads

        const int cend = (cbase + CHUNK < wend) ? cbase + CHUNK : wend;
        int e0 = (lo > cbase) ? lo : cbase;       // this node's slice of chunk
        int e1 = (hi < cend)  ? hi : cend;

        for (int e = e0; e < e1; e += 4) {
            const int last = e1 - 1;
            int i0 = e - cbase;
            int i1 = ((e + 1 <= last) ? e + 1 : last) - cbase;
            int i2 = ((e + 2 <= last) ? e + 2 : last) - cbase;
            int i3 = ((e + 3 <= last) ? e + 3 : last) - cbase;

            int c0 = s_cols[w][i0], c1 = s_cols[w][i1];
            int c2 = s_cols[w][i2], c3 = s_cols[w][i3];

            float v0 = s_vals[w][i0];
            float v1 = (e + 1 < e1) ? s_vals[w][i1] : 0.f;
            float v2 = (e + 2 < e1) ? s_vals[w][i2] : 0.f;
            float v3 = (e + 3 < e1) ? s_vals[w][i3] : 0.f;

            // 4 independent dwordx4 gathers; each instruction covers 8 rows
            uint4 m0 = ebf4[c0 * 8 + t];
            uint4 m1 = ebf4[c1 * 8 + t];
            uint4 m2 = ebf4[c2 * 8 + t];
            uint4 m3 = ebf4[c3 * 8 + t];

            acc0.x += v0 * bflo(m0.x); acc0.y += v0 * bfhi(m0.x);
            acc0.z += v0 * bflo(m0.y); acc0.w += v0 * bfhi(m0.y);
            acc1.x += v0 * bflo(m0.z); acc1.y += v0 * bfhi(m0.z);
            acc1.z += v0 * bflo(m0.w); acc1.w += v0 * bfhi(m0.w);

            acc0.x += v1 * bflo(m1.x); acc0.y += v1 * bfhi(m1.x);
            acc0.z += v1 * bflo(m1.y); acc0.w += v1 * bfhi(m1.y);
            acc1.x += v1 * bflo(m1.z); acc1.y += v1 * bfhi(m1.z);
            acc1.z += v1 * bflo(m1.w); acc1.w += v1 * bfhi(m1.w);

            acc0.x += v2 * bflo(m2.x); acc0.y += v2 * bfhi(m2.x);
            acc0.z += v2 * bflo(m2.y); acc0.w += v2 * bfhi(m2.y);
            acc1.x += v2 * bflo(m2.z); acc1.y += v2 * bfhi(m2.z);
            acc1.z += v2 * bflo(m2.w); acc1.w += v2 * bfhi(m2.w);

            acc0.x += v3 * bflo(m3.x); acc0.y += v3 * bfhi(m3.x);
            acc0.z += v3 * bflo(m3.y); acc0.w += v3 * bfhi(m3.y);
            acc1.x += v3 * bflo(m3.z); acc1.y += v3 * bfhi(m3.z);
            acc1.z += v3 * bflo(m3.w); acc1.w += v3 * bfhi(m3.w);
        }
        __builtin_amdgcn_wave_barrier();  // keep next chunk's writes after reads
    }

    long ob = (long)node * 16 + 2 * t;    // lane writes features [8t, 8t+8)
    out4[ob]     = acc0;
    out4[ob + 1] = acc1;
}

extern "C" void kernel_launch(void* const* d_in, const int* in_sizes, int n_in,
                              void* d_out, int out_size, void* d_ws, size_t ws_size,
                              hipStream_t stream) {
    const int*   rows   = (const int*)d_in[0];
    const int*   cols   = (const int*)d_in[1];
    const float* vals   = (const float*)d_in[2];
    const float* embeds = (const float*)d_in[3];
    float4*      out4   = (float4*)d_out;

    const int n_edges = in_sizes[0];
    const int n_nodes = out_size / D;                 // 100000
    const int n_feat  = in_sizes[3];                  // 6,400,000

    char*  ws        = (char*)d_ws;
    uint4* ebf_table = (uint4*)ws;                    // 12.8 MB bf16 table
    int*   row_ptr   = (int*)(ws + (size_t)n_feat * 2);

    // 1) merged prep: f32->bf16 table + CSR row pointers
    int n8         = n_feat / 8;                      // 800,000 groups
    int cvt_blocks = (n8 + 255) / 256;                // 3125
    int row_blocks = (n_edges + 255) / 256;           // 6250
    prep_kernel<<<cvt_blocks + row_blocks, 256, 0, stream>>>(
        (const uint4*)embeds, ebf_table, n8,
        rows, row_ptr, n_edges, n_nodes, cvt_blocks);

    // 2) node-centric SpMM: one 8-lane subgroup per node
    int waves  = (n_nodes + 7) / 8;                   // 8 nodes per wave
    int blocks = (waves + 3) / 4;                     // 4 waves per block
    spmm_node_kernel<<<blocks, 256, 0, stream>>>(
        row_ptr, cols, vals, ebf_table, out4, n_nodes);
}

// Round 2
// 119.614 us; speedup vs baseline: 1.0381x; 1.0086x over previous
//
#include <hip/hip_runtime.h>
#include <hip/hip_bf16.h>

// GCN SpMM: out[i,d] = sum_{e: rows[e]==i} vals[e] * embeds[cols[e], d]
// rows sorted ascending. E=1.6M, N=100k, D=64.
//
// Round 9:
//  1) prep_kernel (merged): blocks [0,cvt_blocks) convert embeds f32->bf16
//     (12.8 MB table in d_ws); remaining blocks build CSR row_ptr[N+1].
//  2) spmm_node_kernel: 8-lane subgroups (8 nodes/wave) + wave-private LDS
//     staging of cols/vals (round 8), PLUS unroll-8 gather pipeline:
//     8 independent dwordx4 gathers in flight per subgroup (was 4),
//     doubling per-SIMD memory-level parallelism (16 -> 32 outstanding
//     gather instructions at 4 waves/SIMD). Rationale: round-8 showed the
//     loop is not VMEM-issue-bound; gathers are LLC-latency-bound, so
//     deepen the pipeline. __launch_bounds__(256,4) pins the 128-VGPR
//     class (no spill, occupancy unchanged). Clamped tail gathers hit the
//     last valid edge's cacheline -> no extra sector traffic.

constexpr int D = 64;

__device__ __forceinline__ unsigned bf16rnd(unsigned u) {
    // round-to-nearest-even f32 -> bf16 (low 16 bits)
    return (u + 0x7FFFu + ((u >> 16) & 1u)) >> 16;
}

__global__ __launch_bounds__(256) void prep_kernel(
    const uint4* __restrict__ src,   // f32 embeds as uint4 (2 per 8-float group)
    uint4* __restrict__ dst,         // bf16 table as uint4 (8 bf16)
    int n8,
    const int* __restrict__ rows, int* __restrict__ row_ptr,
    int n_edges, int n_nodes, int cvt_blocks)
{
    if ((int)blockIdx.x < cvt_blocks) {
        int i = blockIdx.x * 256 + threadIdx.x;
        if (i >= n8) return;
        uint4 a = src[2 * i];
        uint4 b = src[2 * i + 1];
        uint4 o;
        o.x = bf16rnd(a.x) | (bf16rnd(a.y) << 16);
        o.y = bf16rnd(a.z) | (bf16rnd(a.w) << 16);
        o.z = bf16rnd(b.x) | (bf16rnd(b.y) << 16);
        o.w = bf16rnd(b.z) | (bf16rnd(b.w) << 16);
        dst[i] = o;
    } else {
        int e = (blockIdx.x - cvt_blocks) * 256 + threadIdx.x;
        if (e >= n_edges) return;
        int r_cur  = rows[e];
        int r_prev = (e == 0) ? -1 : rows[e - 1];
        for (int r = r_prev + 1; r <= r_cur; ++r) row_ptr[r] = e;
        if (e == n_edges - 1)
            for (int r = r_cur + 1; r <= n_nodes; ++r) row_ptr[r] = n_edges;
    }
}

__device__ __forceinline__ float bflo(unsigned w) {
    union { unsigned u; float f; } x; x.u = w << 16; return x.f;
}
__device__ __forceinline__ float bfhi(unsigned w) {
    union { unsigned u; float f; } x; x.u = w & 0xFFFF0000u; return x.f;
}

__global__ __launch_bounds__(256, 4) void spmm_node_kernel(
    const int* __restrict__ row_ptr,
    const int* __restrict__ cols,
    const float* __restrict__ vals,
    const uint4* __restrict__ ebf4,       // bf16 [N,64]: row = 8 uint4
    float4* __restrict__ out4,            // [N,16] float4 view
    int n_nodes)
{
    constexpr int CHUNK = 256;            // edges staged per wave per pass
    __shared__ int   s_cols[4][CHUNK];    // 4 waves/block, wave-private
    __shared__ float s_vals[4][CHUNK];

    const int lane = threadIdx.x & 63;
    const int t    = lane & 7;            // 16B chunk within row
    const int s    = lane >> 3;           // subgroup (node) within wave
    const int w    = threadIdx.x >> 6;    // wave within block
    const int wave = blockIdx.x * (blockDim.x >> 6) + w;
    const int node = wave * 8 + s;
    if (node >= n_nodes) return;

    const int nb    = wave * 8;
    const int nbhi  = (nb + 8 <= n_nodes) ? nb + 8 : n_nodes;
    const int wbase = row_ptr[nb];        // wave's contiguous edge span
    const int wend  = row_ptr[nbhi];
    const int lo    = row_ptr[node];
    const int hi    = row_ptr[node + 1];

    float4 acc0 = make_float4(0.f, 0.f, 0.f, 0.f);
    float4 acc1 = make_float4(0.f, 0.f, 0.f, 0.f);

    for (int cbase = wbase; cbase < wend; cbase += CHUNK) {
        // ---- cooperative, coalesced staging of this wave's edge chunk ----
        #pragma unroll
        for (int j = 0; j < CHUNK; j += 64) {
            if (cbase + j >= wend) break;         // wave-uniform early out
            int idx = cbase + j + lane;
            if (idx < wend) {
                s_cols[w][j + lane] = cols[idx];
                s_vals[w][j + lane] = vals[idx];
            }
        }
        __builtin_amdgcn_wave_barrier();  // pin ds_writes before ds_reads

        const int cend = (cbase + CHUNK < wend) ? cbase + CHUNK : wend;
        int e0 = (lo > cbase) ? lo : cbase;       // this node's slice of chunk
        int e1 = (hi < cend)  ? hi : cend;

        for (int e = e0; e < e1; e += 8) {
            const int last = e1 - 1;
            int i0 = e - cbase;
            int i1 = ((e + 1 <= last) ? e + 1 : last) - cbase;
            int i2 = ((e + 2 <= last) ? e + 2 : last) - cbase;
            int i3 = ((e + 3 <= last) ? e + 3 : last) - cbase;
            int i4 = ((e + 4 <= last) ? e + 4 : last) - cbase;
            int i5 = ((e + 5 <= last) ? e + 5 : last) - cbase;
            int i6 = ((e + 6 <= last) ? e + 6 : last) - cbase;
            int i7 = ((e + 7 <= last) ? e + 7 : last) - cbase;

            int c0 = s_cols[w][i0], c1 = s_cols[w][i1];
            int c2 = s_cols[w][i2], c3 = s_cols[w][i3];
            int c4 = s_cols[w][i4], c5 = s_cols[w][i5];
            int c6 = s_cols[w][i6], c7 = s_cols[w][i7];

            float v0 = s_vals[w][i0];
            float v1 = (e + 1 < e1) ? s_vals[w][i1] : 0.f;
            float v2 = (e + 2 < e1) ? s_vals[w][i2] : 0.f;
            float v3 = (e + 3 < e1) ? s_vals[w][i3] : 0.f;
            float v4 = (e + 4 < e1) ? s_vals[w][i4] : 0.f;
            float v5 = (e + 5 < e1) ? s_vals[w][i5] : 0.f;
            float v6 = (e + 6 < e1) ? s_vals[w][i6] : 0.f;
            float v7 = (e + 7 < e1) ? s_vals[w][i7] : 0.f;

            // 8 independent dwordx4 gathers in flight; each covers 8 rows
            uint4 m0 = ebf4[c0 * 8 + t];
            uint4 m1 = ebf4[c1 * 8 + t];
            uint4 m2 = ebf4[c2 * 8 + t];
            uint4 m3 = ebf4[c3 * 8 + t];
            uint4 m4 = ebf4[c4 * 8 + t];
            uint4 m5 = ebf4[c5 * 8 + t];
            uint4 m6 = ebf4[c6 * 8 + t];
            uint4 m7 = ebf4[c7 * 8 + t];

            acc0.x += v0 * bflo(m0.x); acc0.y += v0 * bfhi(m0.x);
            acc0.z += v0 * bflo(m0.y); acc0.w += v0 * bfhi(m0.y);
            acc1.x += v0 * bflo(m0.z); acc1.y += v0 * bfhi(m0.z);
            acc1.z += v0 * bflo(m0.w); acc1.w += v0 * bfhi(m0.w);

            acc0.x += v1 * bflo(m1.x); acc0.y += v1 * bfhi(m1.x);
            acc0.z += v1 * bflo(m1.y); acc0.w += v1 * bfhi(m1.y);
            acc1.x += v1 * bflo(m1.z); acc1.y += v1 * bfhi(m1.z);
            acc1.z += v1 * bflo(m1.w); acc1.w += v1 * bfhi(m1.w);

            acc0.x += v2 * bflo(m2.x); acc0.y += v2 * bfhi(m2.x);
            acc0.z += v2 * bflo(m2.y); acc0.w += v2 * bfhi(m2.y);
            acc1.x += v2 * bflo(m2.z); acc1.y += v2 * bfhi(m2.z);
            acc1.z += v2 * bflo(m2.w); acc1.w += v2 * bfhi(m2.w);

            acc0.x += v3 * bflo(m3.x); acc0.y += v3 * bfhi(m3.x);
            acc0.z += v3 * bflo(m3.y); acc0.w += v3 * bfhi(m3.y);
            acc1.x += v3 * bflo(m3.z); acc1.y += v3 * bfhi(m3.z);
            acc1.z += v3 * bflo(m3.w); acc1.w += v3 * bfhi(m3.w);

            acc0.x += v4 * bflo(m4.x); acc0.y += v4 * bfhi(m4.x);
            acc0.z += v4 * bflo(m4.y); acc0.w += v4 * bfhi(m4.y);
            acc1.x += v4 * bflo(m4.z); acc1.y += v4 * bfhi(m4.z);
            acc1.z += v4 * bflo(m4.w); acc1.w += v4 * bfhi(m4.w);

            acc0.x += v5 * bflo(m5.x); acc0.y += v5 * bfhi(m5.x);
            acc0.z += v5 * bflo(m5.y); acc0.w += v5 * bfhi(m5.y);
            acc1.x += v5 * bflo(m5.z); acc1.y += v5 * bfhi(m5.z);
            acc1.z += v5 * bflo(m5.w); acc1.w += v5 * bfhi(m5.w);

            acc0.x += v6 * bflo(m6.x); acc0.y += v6 * bfhi(m6.x);
            acc0.z += v6 * bflo(m6.y); acc0.w += v6 * bfhi(m6.y);
            acc1.x += v6 * bflo(m6.z); acc1.y += v6 * bfhi(m6.z);
            acc1.z += v6 * bflo(m6.w); acc1.w += v6 * bfhi(m6.w);

            acc0.x += v7 * bflo(m7.x); acc0.y += v7 * bfhi(m7.x);
            acc0.z += v7 * bflo(m7.y); acc0.w += v7 * bfhi(m7.y);
            acc1.x += v7 * bflo(m7.z); acc1.y += v7 * bfhi(m7.z);
            acc1.z += v7 * bflo(m7.w); acc1.w += v7 * bfhi(m7.w);
        }
        __builtin_amdgcn_wave_barrier();  // keep next chunk's writes after reads
    }

    long ob = (long)node * 16 + 2 * t;    // lane writes features [8t, 8t+8)
    out4[ob]     = acc0;
    out4[ob + 1] = acc1;
}

extern "C" void kernel_launch(void* const* d_in, const int* in_sizes, int n_in,
                              void* d_out, int out_size, void* d_ws, size_t ws_size,
                              hipStream_t stream) {
    const int*   rows   = (const int*)d_in[0];
    const int*   cols   = (const int*)d_in[1];
    const float* vals   = (const float*)d_in[2];
    const float* embeds = (const float*)d_in[3];
    float4*      out4   = (float4*)d_out;

    const int n_edges = in_sizes[0];
    const int n_nodes = out_size / D;                 // 100000
    const int n_feat  = in_sizes[3];                  // 6,400,000

    char*  ws        = (char*)d_ws;
    uint4* ebf_table = (uint4*)ws;                    // 12.8 MB bf16 table
    int*   row_ptr   = (int*)(ws + (size_t)n_feat * 2);

    // 1) merged prep: f32->bf16 table + CSR row pointers
    int n8         = n_feat / 8;                      // 800,000 groups
    int cvt_blocks = (n8 + 255) / 256;                // 3125
    int row_blocks = (n_edges + 255) / 256;           // 6250
    prep_kernel<<<cvt_blocks + row_blocks, 256, 0, stream>>>(
        (const uint4*)embeds, ebf_table, n8,
        rows, row_ptr, n_edges, n_nodes, cvt_blocks);

    // 2) node-centric SpMM: one 8-lane subgroup per node
    int waves  = (n_nodes + 7) / 8;                   // 8 nodes per wave
    int blocks = (waves + 3) / 4;                     // 4 waves per block
    spmm_node_kernel<<<blocks, 256, 0, stream>>>(
        row_ptr, cols, vals, ebf_table, out4, n_nodes);
}